// Round 1
// baseline (574.098 us; speedup 1.0000x reference)
//
#include <hip/hip_runtime.h>
#include <math.h>

#define TPB 512

// Branchless GELU via Abramowitz-Stegun 7.1.26 erf (|abs err| <= 1.5e-7,
// negligible vs the harness's observed absmax 7.8e-3). ~14 VALU instrs,
// no branches -- replaces ~35-instr inlined library erff at 128 call sites.
__device__ __forceinline__ float gelu_fast(float t) {
    float z = t * 0.70710678118654752440f;     // t / sqrt(2)
    float a = fabsf(z);
    float tau = __builtin_amdgcn_rcpf(fmaf(0.3275911f, a, 1.0f)); // 1/(1+p*a), 1ulp
    float poly = fmaf(1.061405429f, tau, -1.453152027f);
    poly = fmaf(poly, tau, 1.421413741f);
    poly = fmaf(poly, tau, -0.284496736f);
    poly = fmaf(poly, tau, 0.254829592f);
    poly = poly * tau;
    float e = __expf(-a * a);                  // v_exp_f32
    float erf_a = fmaf(-poly, e, 1.0f);        // erf(|z|)
    float erf_z = copysignf(erf_a, z);
    return 0.5f * t * (1.0f + erf_z);
}

// TPB=512 + min 4 waves/EU: 2 blocks/CU (86KB LDS <= 160KB), 16 waves/CU.
// At TPB=256 the 43KB LDS capped us at 3 blocks/CU = 12 waves/CU.
__global__ __launch_bounds__(TPB, 4) void walsh_mlp_kernel(
    const int* __restrict__ tt,
    const float* __restrict__ W1, const float* __restrict__ b1,
    const float* __restrict__ g1, const float* __restrict__ be1,
    const float* __restrict__ W2, const float* __restrict__ b2,
    const float* __restrict__ g2, const float* __restrict__ be2,
    const float* __restrict__ W3, const float* __restrict__ b3,
    float* __restrict__ out, int nrows)
{
    __shared__ float sW1[33 * 64];
    __shared__ float sW2[64 * 64];
    __shared__ float sW3[64 * 64];
    __shared__ float sP[7 * 64];  // b1,g1,be1,b2,g2,be2,b3

    const int tid = threadIdx.x;
    for (int i = tid; i < 33 * 64; i += TPB) sW1[i] = W1[i];
    for (int i = tid; i < 64 * 64; i += TPB) sW2[i] = W2[i];
    for (int i = tid; i < 64 * 64; i += TPB) sW3[i] = W3[i];
    if (tid < 64) {
        sP[tid]       = b1[tid];
        sP[64 + tid]  = g1[tid];
        sP[128 + tid] = be1[tid];
        sP[192 + tid] = b2[tid];
        sP[256 + tid] = g2[tid];
        sP[320 + tid] = be2[tid];
        sP[384 + tid] = b3[tid];
    }
    __syncthreads();

    const int row = blockIdx.x * TPB + tid;
    if (row >= nrows) return;

    // ---- load truth table row, convert to polar +-1 ----
    float v[64];
    const int4* t4 = reinterpret_cast<const int4*>(tt + (size_t)row * 64);
#pragma unroll
    for (int q = 0; q < 16; ++q) {
        int4 a = t4[q];
        v[4 * q + 0] = 1.0f - 2.0f * (float)a.x;
        v[4 * q + 1] = 1.0f - 2.0f * (float)a.y;
        v[4 * q + 2] = 1.0f - 2.0f * (float)a.z;
        v[4 * q + 3] = 1.0f - 2.0f * (float)a.w;
    }

    // ---- in-register FWHT (Sylvester order; == f @ H) ----
#pragma unroll
    for (int h = 1; h < 64; h <<= 1) {
#pragma unroll
        for (int i = 0; i < 64; ++i) {
            if ((i & h) == 0) {
                float a = v[i], b = v[i | h];
                v[i] = a + b;
                v[i | h] = a - b;
            }
        }
    }

    const float inv_n = 1.0f / 64.0f;
    float f[33];
    // key coefficients: indices 0,1,2,4,8,16,32,63
    f[0] = v[0] * inv_n;  f[1] = v[1] * inv_n;  f[2] = v[2] * inv_n;
    f[3] = v[4] * inv_n;  f[4] = v[8] * inv_n;  f[5] = v[16] * inv_n;
    f[6] = v[32] * inv_n; f[7] = v[63] * inv_n;

    // ---- abs in place + single stats pass ----
    // walsh values are exact even integers in [-64,64] -> all threshold
    // comparisons below are unambiguous.
    // Parseval: sum(walsh^2) == 64*64 == 4096 exactly (fp32-exact since all
    // partial sums are integers < 2^24), and 4096.0f + 1e-10f == 4096.0f in
    // fp32, so sumsq need not be computed at all:
    //   l2   = sqrt(4096)/4096 = 1/64          (constant)
    //   pinv = 1/4096 = 2^-12                  (exact; mul == ref's div)
    float sumabs = 0.f, maxab = 0.f, cnt_sp = 0.f, cnt_lg = 0.f;
    float sum_hw = 0.f, bent = 0.f;
#pragma unroll
    for (int i = 0; i < 64; ++i) {
        float a = fabsf(v[i]);
        v[i] = a;
        sumabs += a;
        maxab = fmaxf(maxab, a);
        cnt_sp += (a < 6.4f) ? 1.0f : 0.0f;
        sum_hw += (a < 6.4f) ? 0.0f : (float)__popc(i);  // mask = (a > 6.4) exactly
        cnt_lg += (a > 32.0f) ? 1.0f : 0.0f;
        bent += fabsf(a - 8.0f);
    }
    const float pinv = 2.44140625e-4f;  // 1/4096, exact power of two
    float ent = 0.0f;
#pragma unroll
    for (int i = 0; i < 64; ++i) {
        float p = (v[i] * v[i]) * pinv;
        ent -= p * __logf(p + 1e-10f);
    }

    f[8]  = cnt_sp * inv_n;                                   // sparsity
    f[9]  = maxab * inv_n;                                    // max_mag
    f[10] = sumabs * (1.0f / 4096.0f);                        // l1
    f[11] = 0.015625f;                                        // l2 == 1/64 always
    f[12] = ent * 0.24044917348149316f;                       // entropy / ln(64)
    f[13] = (cnt_lg >= 0.5f && cnt_lg <= 2.5f) ? 1.0f : 0.0f; // is_linear
    f[14] = fmaxf(0.0f, 0.5f - maxab * (1.0f / 128.0f)) * 2.0f; // nonlinearity
    f[15] = sum_hw / (64.0f - cnt_sp + 1e-10f) * (1.0f / 6.0f); // degree
    f[16] = (bent < 51.2f) ? 1.0f : 0.0f;                     // is_bent (bent/512 < 0.1)

    // ---- top-16: Batcher-sort each 16-block desc, then 3 bitonic top-merges.
    // 4*63 + 3*(16 max + 32 CE) network vs full Batcher-64 (543 CE): same
    // top-16 multiset, sorted descending, ~350 fewer instructions. ----
    {
        auto CE = [&](int u, int w) {
            float x = v[u], y = v[w];
            v[u] = fmaxf(x, y);
            v[w] = fminf(x, y);
        };
#pragma unroll
        for (int b = 0; b < 4; ++b) {
            const int base = b * 16;
#pragma unroll
            for (int p = 1; p < 16; p <<= 1) {
#pragma unroll
                for (int k = p; k >= 1; k >>= 1) {
#pragma unroll
                    for (int j = k & (p - 1); j + k < 16; j += 2 * k) {
#pragma unroll
                        for (int i = 0; i < k; ++i) {
                            if (i + j + k < 16) {
                                if ((i + j) / (2 * p) == (i + j + k) / (2 * p))
                                    CE(base + i + j, base + i + j + k);
                            }
                        }
                    }
                }
            }
        }
        // merge two descending 16-lists; top-16 lands (sorted desc) at a0.
        // t[i] = max(A[i], B[15-i]) is the top half of the first bitonic-merge
        // stage (lower half never needed -> mins dropped), and is bitonic;
        // the d=8,4,2,1 cleanup sorts it descending.
        auto MERGE = [&](int a0, int b0) {
#pragma unroll
            for (int i = 0; i < 16; ++i)
                v[a0 + i] = fmaxf(v[a0 + i], v[b0 + 15 - i]);
#pragma unroll
            for (int d = 8; d >= 1; d >>= 1) {
#pragma unroll
                for (int i = 0; i < 16; ++i) {
                    if ((i & d) == 0) CE(a0 + i, a0 + i + d);
                }
            }
        };
        MERGE(0, 16);
        MERGE(32, 48);
        MERGE(0, 32);
    }
#pragma unroll
    for (int t = 0; t < 16; ++t) f[17 + t] = v[t] * inv_n;

    // ================= MLP =================
    // layer 1: feats[33] @ W1[33,64] + b1
    float h[64];
#pragma unroll
    for (int j = 0; j < 64; ++j) h[j] = sP[j];
#pragma unroll
    for (int k = 0; k < 33; ++k) {
        float fv = f[k];
        const float4* w4 = reinterpret_cast<const float4*>(sW1 + k * 64);
#pragma unroll
        for (int j4 = 0; j4 < 16; ++j4) {
            float4 w = w4[j4];
            h[4 * j4 + 0] += fv * w.x;
            h[4 * j4 + 1] += fv * w.y;
            h[4 * j4 + 2] += fv * w.z;
            h[4 * j4 + 3] += fv * w.w;
        }
    }

    // LN1 + GELU (8-way striped tree reduction: depth ~8+3 instead of 63)
    float x[64];
    {
        float a0 = 0.f, a1 = 0.f, a2 = 0.f, a3 = 0.f,
              a4 = 0.f, a5 = 0.f, a6 = 0.f, a7 = 0.f;
#pragma unroll
        for (int j = 0; j < 64; j += 8) {
            a0 += h[j + 0]; a1 += h[j + 1]; a2 += h[j + 2]; a3 += h[j + 3];
            a4 += h[j + 4]; a5 += h[j + 5]; a6 += h[j + 6]; a7 += h[j + 7];
        }
        float m = (((a0 + a1) + (a2 + a3)) + ((a4 + a5) + (a6 + a7))) * inv_n;
        a0 = a1 = a2 = a3 = a4 = a5 = a6 = a7 = 0.f;
#pragma unroll
        for (int j = 0; j < 64; j += 8) {
            float d0 = h[j + 0] - m, d1 = h[j + 1] - m, d2 = h[j + 2] - m, d3 = h[j + 3] - m;
            float d4 = h[j + 4] - m, d5 = h[j + 5] - m, d6 = h[j + 6] - m, d7 = h[j + 7] - m;
            a0 = fmaf(d0, d0, a0); a1 = fmaf(d1, d1, a1);
            a2 = fmaf(d2, d2, a2); a3 = fmaf(d3, d3, a3);
            a4 = fmaf(d4, d4, a4); a5 = fmaf(d5, d5, a5);
            a6 = fmaf(d6, d6, a6); a7 = fmaf(d7, d7, a7);
        }
        float var = (((a0 + a1) + (a2 + a3)) + ((a4 + a5) + (a6 + a7))) * inv_n;
        float rstd = rsqrtf(var + 1e-5f);
#pragma unroll
        for (int j = 0; j < 64; ++j) {
            float t = (h[j] - m) * rstd * sP[64 + j] + sP[128 + j];
            x[j] = gelu_fast(t);
        }
    }

    // layer 2: x[64] @ W2[64,64] + b2
#pragma unroll
    for (int j = 0; j < 64; ++j) h[j] = sP[192 + j];
#pragma unroll
    for (int k = 0; k < 64; ++k) {
        float fv = x[k];
        const float4* w4 = reinterpret_cast<const float4*>(sW2 + k * 64);
#pragma unroll
        for (int j4 = 0; j4 < 16; ++j4) {
            float4 w = w4[j4];
            h[4 * j4 + 0] += fv * w.x;
            h[4 * j4 + 1] += fv * w.y;
            h[4 * j4 + 2] += fv * w.z;
            h[4 * j4 + 3] += fv * w.w;
        }
    }

    // LN2 + GELU
    {
        float a0 = 0.f, a1 = 0.f, a2 = 0.f, a3 = 0.f,
              a4 = 0.f, a5 = 0.f, a6 = 0.f, a7 = 0.f;
#pragma unroll
        for (int j = 0; j < 64; j += 8) {
            a0 += h[j + 0]; a1 += h[j + 1]; a2 += h[j + 2]; a3 += h[j + 3];
            a4 += h[j + 4]; a5 += h[j + 5]; a6 += h[j + 6]; a7 += h[j + 7];
        }
        float m = (((a0 + a1) + (a2 + a3)) + ((a4 + a5) + (a6 + a7))) * inv_n;
        a0 = a1 = a2 = a3 = a4 = a5 = a6 = a7 = 0.f;
#pragma unroll
        for (int j = 0; j < 64; j += 8) {
            float d0 = h[j + 0] - m, d1 = h[j + 1] - m, d2 = h[j + 2] - m, d3 = h[j + 3] - m;
            float d4 = h[j + 4] - m, d5 = h[j + 5] - m, d6 = h[j + 6] - m, d7 = h[j + 7] - m;
            a0 = fmaf(d0, d0, a0); a1 = fmaf(d1, d1, a1);
            a2 = fmaf(d2, d2, a2); a3 = fmaf(d3, d3, a3);
            a4 = fmaf(d4, d4, a4); a5 = fmaf(d5, d5, a5);
            a6 = fmaf(d6, d6, a6); a7 = fmaf(d7, d7, a7);
        }
        float var = (((a0 + a1) + (a2 + a3)) + ((a4 + a5) + (a6 + a7))) * inv_n;
        float rstd = rsqrtf(var + 1e-5f);
#pragma unroll
        for (int j = 0; j < 64; ++j) {
            float t = (h[j] - m) * rstd * sP[256 + j] + sP[320 + j];
            x[j] = gelu_fast(t);
        }
    }

    // layer 3: x[64] @ W3[64,64] + b3
#pragma unroll
    for (int j = 0; j < 64; ++j) h[j] = sP[384 + j];
#pragma unroll
    for (int k = 0; k < 64; ++k) {
        float fv = x[k];
        const float4* w4 = reinterpret_cast<const float4*>(sW3 + k * 64);
#pragma unroll
        for (int j4 = 0; j4 < 16; ++j4) {
            float4 w = w4[j4];
            h[4 * j4 + 0] += fv * w.x;
            h[4 * j4 + 1] += fv * w.y;
            h[4 * j4 + 2] += fv * w.z;
            h[4 * j4 + 3] += fv * w.w;
        }
    }

    // ---- store 64 fp32 outputs ----
    float4* o4 = reinterpret_cast<float4*>(out + (size_t)row * 64);
#pragma unroll
    for (int q = 0; q < 16; ++q) {
        float4 r;
        r.x = h[4 * q + 0];
        r.y = h[4 * q + 1];
        r.z = h[4 * q + 2];
        r.w = h[4 * q + 3];
        o4[q] = r;
    }
}

extern "C" void kernel_launch(void* const* d_in, const int* in_sizes, int n_in,
                              void* d_out, int out_size, void* d_ws, size_t ws_size,
                              hipStream_t stream) {
    const int*   tt  = (const int*)d_in[0];
    // d_in[1] is the Hadamard matrix H -- unused (we do an in-register FWHT)
    const float* W1  = (const float*)d_in[2];
    const float* b1  = (const float*)d_in[3];
    const float* g1  = (const float*)d_in[4];
    const float* be1 = (const float*)d_in[5];
    const float* W2  = (const float*)d_in[6];
    const float* b2  = (const float*)d_in[7];
    const float* g2  = (const float*)d_in[8];
    const float* be2 = (const float*)d_in[9];
    const float* W3  = (const float*)d_in[10];
    const float* b3  = (const float*)d_in[11];
    float* out = (float*)d_out;

    const int nrows = in_sizes[0] / 64;
    const int grid = (nrows + TPB - 1) / TPB;
    hipLaunchKernelGGL(walsh_mlp_kernel, dim3(grid), dim3(TPB), 0, stream,
                       tt, W1, b1, g1, be1, W2, b2, g2, be2, W3, b3, out, nrows);
}

// Round 2
// 261.481 us; speedup vs baseline: 2.1956x; 2.1956x over previous
//
#include <hip/hip_runtime.h>
#include <math.h>

#define TPB 512

// Branchless GELU via Abramowitz-Stegun 7.1.26 erf (|abs err| <= 1.5e-7,
// negligible vs the harness's observed absmax 7.8e-3). ~14 VALU instrs,
// no branches -- replaces ~35-instr inlined library erff at 128 call sites.
__device__ __forceinline__ float gelu_fast(float t) {
    float z = t * 0.70710678118654752440f;     // t / sqrt(2)
    float a = fabsf(z);
    float tau = __builtin_amdgcn_rcpf(fmaf(0.3275911f, a, 1.0f)); // 1/(1+p*a)
    float poly = fmaf(1.061405429f, tau, -1.453152027f);
    poly = fmaf(poly, tau, 1.421413741f);
    poly = fmaf(poly, tau, -0.284496736f);
    poly = fmaf(poly, tau, 0.254829592f);
    poly = poly * tau;
    float e = __expf(-a * a);                  // v_exp_f32
    float erf_a = fmaf(-poly, e, 1.0f);        // erf(|z|)
    float erf_z = copysignf(erf_a, z);
    return 0.5f * t * (1.0f + erf_z);
}

// __launch_bounds__ 2nd arg behaves as min BLOCKS/CU on hipcc (measured:
// (512,4) forced VGPR=64 = 8 waves/SIMD cap -> catastrophic spill).
// (512,2): 2 blocks x 8 waves = 16 waves/CU = 4 waves/SIMD -> VGPR cap 128,
// which fits this kernel's natural ~120.  LDS 2 x ~43KB = 86KB <= 160KB.
// vs TPB=256 baseline: LDS capped residency at 3 blocks = 12 waves/CU.
__global__ __launch_bounds__(TPB, 2) void walsh_mlp_kernel(
    const int* __restrict__ tt,
    const float* __restrict__ W1, const float* __restrict__ b1,
    const float* __restrict__ g1, const float* __restrict__ be1,
    const float* __restrict__ W2, const float* __restrict__ b2,
    const float* __restrict__ g2, const float* __restrict__ be2,
    const float* __restrict__ W3, const float* __restrict__ b3,
    float* __restrict__ out, int nrows)
{
    __shared__ float sW1[33 * 64];
    __shared__ float sW2[64 * 64];
    __shared__ float sW3[64 * 64];
    __shared__ float sP[7 * 64];   // b1',g1,be1,b2,g2,be2,b3
    __shared__ float entLUT[33];   // -p*log(p+1e-10), p = (2i)^2/4096

    const int tid = threadIdx.x;
    for (int i = tid; i < 33 * 64; i += TPB) sW1[i] = W1[i];
    for (int i = tid; i < 64 * 64; i += TPB) sW2[i] = W2[i];
    for (int i = tid; i < 64 * 64; i += TPB) sW3[i] = W3[i];
    if (tid < 64) {
        // Parseval: feature 11 (l2) is the constant 1/64 for EVERY row, so
        // its W1 row is a constant bias contribution -> fold into b1.
        sP[tid]       = b1[tid] + 0.015625f * W1[11 * 64 + tid];
        sP[64 + tid]  = g1[tid];
        sP[128 + tid] = be1[tid];
        sP[192 + tid] = b2[tid];
        sP[256 + tid] = g2[tid];
        sP[320 + tid] = be2[tid];
        sP[384 + tid] = b3[tid];
    }
    if (tid < 33) {
        // walsh |coeff| is an even integer 2*tid in [0,64]; precompute the
        // entropy term exactly as the per-element formula would.
        float a = 2.0f * (float)tid;
        float p = (a * a) * 2.44140625e-4f;    // /4096 exact
        entLUT[tid] = -(p * __logf(p + 1e-10f));
    }
    __syncthreads();

    const int row = blockIdx.x * TPB + tid;
    if (row >= nrows) return;

    // ---- load truth table row, convert to polar +-1 ----
    float v[64];
    const int4* t4 = reinterpret_cast<const int4*>(tt + (size_t)row * 64);
#pragma unroll
    for (int q = 0; q < 16; ++q) {
        int4 a = t4[q];
        v[4 * q + 0] = 1.0f - 2.0f * (float)a.x;
        v[4 * q + 1] = 1.0f - 2.0f * (float)a.y;
        v[4 * q + 2] = 1.0f - 2.0f * (float)a.z;
        v[4 * q + 3] = 1.0f - 2.0f * (float)a.w;
    }

    // ---- in-register FWHT (Sylvester order; == f @ H) ----
#pragma unroll
    for (int h = 1; h < 64; h <<= 1) {
#pragma unroll
        for (int i = 0; i < 64; ++i) {
            if ((i & h) == 0) {
                float a = v[i], b = v[i | h];
                v[i] = a + b;
                v[i | h] = a - b;
            }
        }
    }

    const float inv_n = 1.0f / 64.0f;
    float f[33];
    // key coefficients: indices 0,1,2,4,8,16,32,63
    f[0] = v[0] * inv_n;  f[1] = v[1] * inv_n;  f[2] = v[2] * inv_n;
    f[3] = v[4] * inv_n;  f[4] = v[8] * inv_n;  f[5] = v[16] * inv_n;
    f[6] = v[32] * inv_n; f[7] = v[63] * inv_n;

    // ---- abs in place + single fused stats pass ----
    // walsh values are exact even integers in [-64,64] -> all threshold
    // comparisons are unambiguous; entropy term comes from the LDS LUT.
    float sumabs = 0.f, maxab = 0.f, cnt_sp = 0.f, cnt_lg = 0.f;
    float sum_hw = 0.f, bent = 0.f, ent = 0.f;
#pragma unroll
    for (int i = 0; i < 64; ++i) {
        float a = fabsf(v[i]);
        v[i] = a;
        sumabs += a;
        maxab = fmaxf(maxab, a);
        cnt_sp += (a < 6.4f) ? 1.0f : 0.0f;
        sum_hw += (a < 6.4f) ? 0.0f : (float)__popc(i);  // mask = (a > 6.4) exactly
        cnt_lg += (a > 32.0f) ? 1.0f : 0.0f;
        bent += fabsf(a - 8.0f);
        ent += entLUT[((int)a) >> 1];
    }

    f[8]  = cnt_sp * inv_n;                                   // sparsity
    f[9]  = maxab * inv_n;                                    // max_mag
    f[10] = sumabs * (1.0f / 4096.0f);                        // l1
    f[11] = 0.015625f;  // l2 == 1/64 always (folded into bias; k=11 skipped)
    f[12] = ent * 0.24044917348149316f;                       // entropy / ln(64)
    f[13] = (cnt_lg >= 0.5f && cnt_lg <= 2.5f) ? 1.0f : 0.0f; // is_linear
    f[14] = fmaxf(0.0f, 0.5f - maxab * (1.0f / 128.0f)) * 2.0f; // nonlinearity
    f[15] = sum_hw / (64.0f - cnt_sp + 1e-10f) * (1.0f / 6.0f); // degree
    f[16] = (bent < 51.2f) ? 1.0f : 0.0f;                     // is_bent (bent/512 < 0.1)

    // ---- top-16: Batcher-sort each 16-block desc, then 3 bitonic top-merges.
    // 4*63 + 3*(16 max + 32 CE) vs full Batcher-64 (543 CE): same top-16
    // multiset, sorted descending, ~350 fewer instructions. ----
    {
        auto CE = [&](int u, int w) {
            float x = v[u], y = v[w];
            v[u] = fmaxf(x, y);
            v[w] = fminf(x, y);
        };
#pragma unroll
        for (int b = 0; b < 4; ++b) {
            const int base = b * 16;
#pragma unroll
            for (int p = 1; p < 16; p <<= 1) {
#pragma unroll
                for (int k = p; k >= 1; k >>= 1) {
#pragma unroll
                    for (int j = k & (p - 1); j + k < 16; j += 2 * k) {
#pragma unroll
                        for (int i = 0; i < k; ++i) {
                            if (i + j + k < 16) {
                                if ((i + j) / (2 * p) == (i + j + k) / (2 * p))
                                    CE(base + i + j, base + i + j + k);
                            }
                        }
                    }
                }
            }
        }
        // merge two descending 16-lists; top-16 lands (sorted desc) at a0.
        auto MERGE = [&](int a0, int b0) {
#pragma unroll
            for (int i = 0; i < 16; ++i)
                v[a0 + i] = fmaxf(v[a0 + i], v[b0 + 15 - i]);
#pragma unroll
            for (int d = 8; d >= 1; d >>= 1) {
#pragma unroll
                for (int i = 0; i < 16; ++i) {
                    if ((i & d) == 0) CE(a0 + i, a0 + i + d);
                }
            }
        };
        MERGE(0, 16);
        MERGE(32, 48);
        MERGE(0, 32);
    }
#pragma unroll
    for (int t = 0; t < 16; ++t) f[17 + t] = v[t] * inv_n;

    // ================= MLP =================
    // layer 1: feats[33] @ W1[33,64] + b1'   (k=11 folded into bias)
    float h[64];
#pragma unroll
    for (int j = 0; j < 64; ++j) h[j] = sP[j];
#pragma unroll
    for (int k = 0; k < 33; ++k) {
        if (k == 11) continue;
        float fv = f[k];
        const float4* w4 = reinterpret_cast<const float4*>(sW1 + k * 64);
#pragma unroll
        for (int j4 = 0; j4 < 16; ++j4) {
            float4 w = w4[j4];
            h[4 * j4 + 0] += fv * w.x;
            h[4 * j4 + 1] += fv * w.y;
            h[4 * j4 + 2] += fv * w.z;
            h[4 * j4 + 3] += fv * w.w;
        }
    }

    // LN1 + GELU (8-way striped tree reduction: depth ~8+3 instead of 63)
    float x[64];
    {
        float a0 = 0.f, a1 = 0.f, a2 = 0.f, a3 = 0.f,
              a4 = 0.f, a5 = 0.f, a6 = 0.f, a7 = 0.f;
#pragma unroll
        for (int j = 0; j < 64; j += 8) {
            a0 += h[j + 0]; a1 += h[j + 1]; a2 += h[j + 2]; a3 += h[j + 3];
            a4 += h[j + 4]; a5 += h[j + 5]; a6 += h[j + 6]; a7 += h[j + 7];
        }
        float m = (((a0 + a1) + (a2 + a3)) + ((a4 + a5) + (a6 + a7))) * inv_n;
        a0 = a1 = a2 = a3 = a4 = a5 = a6 = a7 = 0.f;
#pragma unroll
        for (int j = 0; j < 64; j += 8) {
            float d0 = h[j + 0] - m, d1 = h[j + 1] - m, d2 = h[j + 2] - m, d3 = h[j + 3] - m;
            float d4 = h[j + 4] - m, d5 = h[j + 5] - m, d6 = h[j + 6] - m, d7 = h[j + 7] - m;
            a0 = fmaf(d0, d0, a0); a1 = fmaf(d1, d1, a1);
            a2 = fmaf(d2, d2, a2); a3 = fmaf(d3, d3, a3);
            a4 = fmaf(d4, d4, a4); a5 = fmaf(d5, d5, a5);
            a6 = fmaf(d6, d6, a6); a7 = fmaf(d7, d7, a7);
        }
        float var = (((a0 + a1) + (a2 + a3)) + ((a4 + a5) + (a6 + a7))) * inv_n;
        float rstd = rsqrtf(var + 1e-5f);
#pragma unroll
        for (int j = 0; j < 64; ++j) {
            float t = (h[j] - m) * rstd * sP[64 + j] + sP[128 + j];
            x[j] = gelu_fast(t);
        }
    }

    // layer 2: x[64] @ W2[64,64] + b2
#pragma unroll
    for (int j = 0; j < 64; ++j) h[j] = sP[192 + j];
#pragma unroll
    for (int k = 0; k < 64; ++k) {
        float fv = x[k];
        const float4* w4 = reinterpret_cast<const float4*>(sW2 + k * 64);
#pragma unroll
        for (int j4 = 0; j4 < 16; ++j4) {
            float4 w = w4[j4];
            h[4 * j4 + 0] += fv * w.x;
            h[4 * j4 + 1] += fv * w.y;
            h[4 * j4 + 2] += fv * w.z;
            h[4 * j4 + 3] += fv * w.w;
        }
    }

    // LN2 + GELU
    {
        float a0 = 0.f, a1 = 0.f, a2 = 0.f, a3 = 0.f,
              a4 = 0.f, a5 = 0.f, a6 = 0.f, a7 = 0.f;
#pragma unroll
        for (int j = 0; j < 64; j += 8) {
            a0 += h[j + 0]; a1 += h[j + 1]; a2 += h[j + 2]; a3 += h[j + 3];
            a4 += h[j + 4]; a5 += h[j + 5]; a6 += h[j + 6]; a7 += h[j + 7];
        }
        float m = (((a0 + a1) + (a2 + a3)) + ((a4 + a5) + (a6 + a7))) * inv_n;
        a0 = a1 = a2 = a3 = a4 = a5 = a6 = a7 = 0.f;
#pragma unroll
        for (int j = 0; j < 64; j += 8) {
            float d0 = h[j + 0] - m, d1 = h[j + 1] - m, d2 = h[j + 2] - m, d3 = h[j + 3] - m;
            float d4 = h[j + 4] - m, d5 = h[j + 5] - m, d6 = h[j + 6] - m, d7 = h[j + 7] - m;
            a0 = fmaf(d0, d0, a0); a1 = fmaf(d1, d1, a1);
            a2 = fmaf(d2, d2, a2); a3 = fmaf(d3, d3, a3);
            a4 = fmaf(d4, d4, a4); a5 = fmaf(d5, d5, a5);
            a6 = fmaf(d6, d6, a6); a7 = fmaf(d7, d7, a7);
        }
        float var = (((a0 + a1) + (a2 + a3)) + ((a4 + a5) + (a6 + a7))) * inv_n;
        float rstd = rsqrtf(var + 1e-5f);
#pragma unroll
        for (int j = 0; j < 64; ++j) {
            float t = (h[j] - m) * rstd * sP[256 + j] + sP[320 + j];
            x[j] = gelu_fast(t);
        }
    }

    // layer 3: x[64] @ W3[64,64] + b3
#pragma unroll
    for (int j = 0; j < 64; ++j) h[j] = sP[384 + j];
#pragma unroll
    for (int k = 0; k < 64; ++k) {
        float fv = x[k];
        const float4* w4 = reinterpret_cast<const float4*>(sW3 + k * 64);
#pragma unroll
        for (int j4 = 0; j4 < 16; ++j4) {
            float4 w = w4[j4];
            h[4 * j4 + 0] += fv * w.x;
            h[4 * j4 + 1] += fv * w.y;
            h[4 * j4 + 2] += fv * w.z;
            h[4 * j4 + 3] += fv * w.w;
        }
    }

    // ---- store 64 fp32 outputs ----
    float4* o4 = reinterpret_cast<float4*>(out + (size_t)row * 64);
#pragma unroll
    for (int q = 0; q < 16; ++q) {
        float4 r;
        r.x = h[4 * q + 0];
        r.y = h[4 * q + 1];
        r.z = h[4 * q + 2];
        r.w = h[4 * q + 3];
        o4[q] = r;
    }
}

extern "C" void kernel_launch(void* const* d_in, const int* in_sizes, int n_in,
                              void* d_out, int out_size, void* d_ws, size_t ws_size,
                              hipStream_t stream) {
    const int*   tt  = (const int*)d_in[0];
    // d_in[1] is the Hadamard matrix H -- unused (we do an in-register FWHT)
    const float* W1  = (const float*)d_in[2];
    const float* b1  = (const float*)d_in[3];
    const float* g1  = (const float*)d_in[4];
    const float* be1 = (const float*)d_in[5];
    const float* W2  = (const float*)d_in[6];
    const float* b2  = (const float*)d_in[7];
    const float* g2  = (const float*)d_in[8];
    const float* be2 = (const float*)d_in[9];
    const float* W3  = (const float*)d_in[10];
    const float* b3  = (const float*)d_in[11];
    float* out = (float*)d_out;

    const int nrows = in_sizes[0] / 64;
    const int grid = (nrows + TPB - 1) / TPB;
    hipLaunchKernelGGL(walsh_mlp_kernel, dim3(grid), dim3(TPB), 0, stream,
                       tt, W1, b1, g1, be1, W2, b2, g2, be2, W3, b3, out, nrows);
}

// Round 3
// 155.390 us; speedup vs baseline: 3.6946x; 1.6827x over previous
//
#include <hip/hip_runtime.h>
#include <math.h>

#define TPB 512

typedef _Float16 half8 __attribute__((ext_vector_type(8)));
typedef float f32x4 __attribute__((ext_vector_type(4)));

// Branchless GELU via Abramowitz-Stegun 7.1.26 erf (|abs err| <= 1.5e-7).
__device__ __forceinline__ float gelu_fast(float t) {
    float z = t * 0.70710678118654752440f;     // t / sqrt(2)
    float a = fabsf(z);
    float tau = __builtin_amdgcn_rcpf(fmaf(0.3275911f, a, 1.0f)); // 1/(1+p*a)
    float poly = fmaf(1.061405429f, tau, -1.453152027f);
    poly = fmaf(poly, tau, 1.421413741f);
    poly = fmaf(poly, tau, -0.284496736f);
    poly = fmaf(poly, tau, 0.254829592f);
    poly = poly * tau;
    float e = __expf(-a * a);                  // v_exp_f32
    float erf_a = fmaf(-poly, e, 1.0f);        // erf(|z|)
    float erf_z = copysignf(erf_a, z);
    return 0.5f * t * (1.0f + erf_z);
}

// One MLP layer on a wave's 64x64 tile via mfma_f32_16x16x32_f16.
// A/B K-slot mapping: hardware pairs A-slot(group,e) with B-slot(group,e),
// so ANY consistent ascending-k packing of A and B is correct; only the C/D
// map (col=lane&15, row=(lane>>4)*4+reg -- HW-verified) is relied upon.
// Weights are f16 hi+lo split -> W is exact to ~2^-22 (2 MFMAs per product).
// Bias rides in as the MFMA C-operand. LN is done on the f32 D fragments
// in-register via shfl_xor over the 16-lane group (no lossy f16 dump).
template<bool LAST>
__device__ __forceinline__ void mfma_layer(
    _Float16 (*act)[64],                               // this wave's 64x64 act
    const _Float16 (*Wh)[64], const _Float16 (*Wl)[64],// transposed [n][k]
    const float* bias, const float* gg, const float* bb,
    float* outp, int rowbase, int nrows)
{
    const int l = threadIdx.x & 63;
    const int g = l >> 4, i = l & 15;

    // B fragments: [N-tile][K-step], hi and lo. Reused across all 4 M-tiles.
    half8 Bh[4][2], Bl[4][2];
#pragma unroll
    for (int nt = 0; nt < 4; ++nt) {
#pragma unroll
        for (int s = 0; s < 2; ++s) {
            const int n = 16 * nt + i, k0 = 32 * s + 8 * g;
            Bh[nt][s] = *(const half8*)&Wh[n][k0];
            Bl[nt][s] = *(const half8*)&Wl[n][k0];
        }
    }
    float bv[4], gv[4], bev[4];
#pragma unroll
    for (int nt = 0; nt < 4; ++nt) {
        bv[nt] = bias[16 * nt + i];
        if (!LAST) { gv[nt] = gg[16 * nt + i]; bev[nt] = bb[16 * nt + i]; }
    }
    const bool full = LAST && (rowbase + 63 < nrows);

#pragma unroll
    for (int t = 0; t < 4; ++t) {
        // A fragments for M-tile t (rows 16t..16t+15), K-steps 0,1
        const half8 A0 = *(const half8*)&act[16 * t + i][8 * g];
        const half8 A1 = *(const half8*)&act[16 * t + i][32 + 8 * g];
        f32x4 D[4];
#pragma unroll
        for (int nt = 0; nt < 4; ++nt) {
            f32x4 d = {bv[nt], bv[nt], bv[nt], bv[nt]};
            d = __builtin_amdgcn_mfma_f32_16x16x32_f16(A0, Bh[nt][0], d, 0, 0, 0);
            d = __builtin_amdgcn_mfma_f32_16x16x32_f16(A1, Bh[nt][1], d, 0, 0, 0);
            d = __builtin_amdgcn_mfma_f32_16x16x32_f16(A0, Bl[nt][0], d, 0, 0, 0);
            d = __builtin_amdgcn_mfma_f32_16x16x32_f16(A1, Bl[nt][1], d, 0, 0, 0);
            D[nt] = d;
        }
        if (LAST) {
            // Store D fragments directly to global: row=16t+4g+reg, col=16nt+i
#pragma unroll
            for (int nt = 0; nt < 4; ++nt) {
#pragma unroll
                for (int r = 0; r < 4; ++r) {
                    const int grow = rowbase + 16 * t + 4 * g + r;
                    if (full || grow < nrows)
                        outp[(size_t)grow * 64 + 16 * nt + i] = D[nt][r];
                }
            }
        } else {
            // LN over the row's 64 values: 4 per-lane N-tile partials (per
            // reg=row) + shfl_xor reduce across the 16 lanes of this group.
            f32x4 s4 = (D[0] + D[1]) + (D[2] + D[3]);
#pragma unroll
            for (int m = 1; m < 16; m <<= 1) {
                f32x4 o;
                o[0] = __shfl_xor(s4[0], m);
                o[1] = __shfl_xor(s4[1], m);
                o[2] = __shfl_xor(s4[2], m);
                o[3] = __shfl_xor(s4[3], m);
                s4 += o;
            }
            const f32x4 mean = s4 * 0.015625f;
            f32x4 vv = {0.f, 0.f, 0.f, 0.f};
#pragma unroll
            for (int nt = 0; nt < 4; ++nt) {
                f32x4 dd = D[nt] - mean;
                vv += dd * dd;
            }
#pragma unroll
            for (int m = 1; m < 16; m <<= 1) {
                f32x4 o;
                o[0] = __shfl_xor(vv[0], m);
                o[1] = __shfl_xor(vv[1], m);
                o[2] = __shfl_xor(vv[2], m);
                o[3] = __shfl_xor(vv[3], m);
                vv += o;
            }
            f32x4 rstd;
#pragma unroll
            for (int r = 0; r < 4; ++r)
                rstd[r] = rsqrtf(vv[r] * 0.015625f + 1e-5f);
            // normalize + GELU + write back transposed into act (f16).
            // Output rows of tile t land exactly in rows [16t,16t+16) -- the
            // rows this iteration already consumed, so no intra-layer hazard.
#pragma unroll
            for (int nt = 0; nt < 4; ++nt) {
#pragma unroll
                for (int r = 0; r < 4; ++r) {
                    float xx = (D[nt][r] - mean[r]) * rstd[r] * gv[nt] + bev[nt];
                    act[16 * t + 4 * g + r][16 * nt + i] = (_Float16)gelu_fast(xx);
                }
            }
        }
    }
    if (!LAST) asm volatile("s_waitcnt lgkmcnt(0)" ::: "memory");
}

// 114KB static LDS -> 1 block/CU (8 waves, 2/SIMD). VGPR cap 256.
__global__ __launch_bounds__(TPB, 1) void walsh_mlp_kernel(
    const int* __restrict__ tt,
    const float* __restrict__ W1, const float* __restrict__ b1,
    const float* __restrict__ g1, const float* __restrict__ be1,
    const float* __restrict__ W2, const float* __restrict__ b2,
    const float* __restrict__ g2, const float* __restrict__ be2,
    const float* __restrict__ W3, const float* __restrict__ b3,
    float* __restrict__ out, int nrows)
{
    __shared__ __align__(16) _Float16 sWh[3][64][64];  // [layer][n][k] hi
    __shared__ __align__(16) _Float16 sWl[3][64][64];  // [layer][n][k] lo
    __shared__ __align__(16) _Float16 sAct[8][64][64]; // per-wave act tiles
    __shared__ float sP[7 * 64];   // g1,be1,g2,be2,b1,b2,b3
    __shared__ float entLUT[33];   // -p*log(p+1e-10), p=(2i)^2/4096

    const int tid = threadIdx.x;

    // ---- stage weights: transpose to [n][k], pad K to 64, f16 hi/lo split
    for (int idx = tid; idx < 3 * 4096; idx += TPB) {
        const int L = idx >> 12, rem = idx & 4095, n = rem >> 6, k = rem & 63;
        const float* Wsrc = (L == 0) ? W1 : (L == 1) ? W2 : W3;
        const int K = (L == 0) ? 33 : 64;
        const float val = (k < K) ? Wsrc[k * 64 + n] : 0.0f;
        const _Float16 hi = (_Float16)val;
        sWh[L][n][k] = hi;
        sWl[L][n][k] = (_Float16)(val - (float)hi);
    }
    if (tid < 64) {
        sP[tid]       = g1[tid];
        sP[64 + tid]  = be1[tid];
        sP[128 + tid] = g2[tid];
        sP[192 + tid] = be2[tid];
        sP[256 + tid] = b1[tid];
        sP[320 + tid] = b2[tid];
        sP[384 + tid] = b3[tid];
    }
    if (tid < 33) {
        const float a = 2.0f * (float)tid;
        const float p = (a * a) * 2.44140625e-4f;   // /4096 exact
        entLUT[tid] = -(p * __logf(p + 1e-10f));
    }
    __syncthreads();

    const int row = blockIdx.x * TPB + tid;
    const int rowc = (row < nrows) ? row : (nrows - 1);  // clamp; no early exit

    // ---- load truth table row, convert to polar +-1 ----
    float v[64];
    const int4* t4 = reinterpret_cast<const int4*>(tt + (size_t)rowc * 64);
#pragma unroll
    for (int q = 0; q < 16; ++q) {
        int4 a = t4[q];
        v[4 * q + 0] = 1.0f - 2.0f * (float)a.x;
        v[4 * q + 1] = 1.0f - 2.0f * (float)a.y;
        v[4 * q + 2] = 1.0f - 2.0f * (float)a.z;
        v[4 * q + 3] = 1.0f - 2.0f * (float)a.w;
    }

    // ---- in-register FWHT (Sylvester order; == f @ H) ----
#pragma unroll
    for (int h = 1; h < 64; h <<= 1) {
#pragma unroll
        for (int i = 0; i < 64; ++i) {
            if ((i & h) == 0) {
                float a = v[i], b = v[i | h];
                v[i] = a + b;
                v[i | h] = a - b;
            }
        }
    }

    const float inv_n = 1.0f / 64.0f;
    float f[33];
    f[0] = v[0] * inv_n;  f[1] = v[1] * inv_n;  f[2] = v[2] * inv_n;
    f[3] = v[4] * inv_n;  f[4] = v[8] * inv_n;  f[5] = v[16] * inv_n;
    f[6] = v[32] * inv_n; f[7] = v[63] * inv_n;

    // ---- abs in place + single fused stats pass (walsh vals are exact even
    // ints in [-64,64]; Parseval: sumsq == 4096 exactly -> l2 const) ----
    float sumabs = 0.f, maxab = 0.f, cnt_sp = 0.f, cnt_lg = 0.f;
    float sum_hw = 0.f, bent = 0.f, ent = 0.f;
#pragma unroll
    for (int i = 0; i < 64; ++i) {
        float a = fabsf(v[i]);
        v[i] = a;
        sumabs += a;
        maxab = fmaxf(maxab, a);
        cnt_sp += (a < 6.4f) ? 1.0f : 0.0f;
        sum_hw += (a < 6.4f) ? 0.0f : (float)__popc(i);
        cnt_lg += (a > 32.0f) ? 1.0f : 0.0f;
        bent += fabsf(a - 8.0f);
        ent += entLUT[((int)a) >> 1];
    }

    f[8]  = cnt_sp * inv_n;
    f[9]  = maxab * inv_n;
    f[10] = sumabs * (1.0f / 4096.0f);
    f[11] = 0.015625f;  // l2 == 1/64 always (Parseval)
    f[12] = ent * 0.24044917348149316f;
    f[13] = (cnt_lg >= 0.5f && cnt_lg <= 2.5f) ? 1.0f : 0.0f;
    f[14] = fmaxf(0.0f, 0.5f - maxab * (1.0f / 128.0f)) * 2.0f;
    f[15] = sum_hw / (64.0f - cnt_sp + 1e-10f) * (1.0f / 6.0f);
    f[16] = (bent < 51.2f) ? 1.0f : 0.0f;

    // ---- top-16: Batcher-sort each 16-block desc + 3 bitonic top-merges ----
    {
        auto CE = [&](int u, int w2) {
            float x = v[u], y = v[w2];
            v[u] = fmaxf(x, y);
            v[w2] = fminf(x, y);
        };
#pragma unroll
        for (int b = 0; b < 4; ++b) {
            const int base = b * 16;
#pragma unroll
            for (int p = 1; p < 16; p <<= 1) {
#pragma unroll
                for (int k = p; k >= 1; k >>= 1) {
#pragma unroll
                    for (int j = k & (p - 1); j + k < 16; j += 2 * k) {
#pragma unroll
                        for (int i = 0; i < k; ++i) {
                            if (i + j + k < 16) {
                                if ((i + j) / (2 * p) == (i + j + k) / (2 * p))
                                    CE(base + i + j, base + i + j + k);
                            }
                        }
                    }
                }
            }
        }
        auto MERGE = [&](int a0, int b0) {
#pragma unroll
            for (int i = 0; i < 16; ++i)
                v[a0 + i] = fmaxf(v[a0 + i], v[b0 + 15 - i]);
#pragma unroll
            for (int d = 8; d >= 1; d >>= 1) {
#pragma unroll
                for (int i = 0; i < 16; ++i) {
                    if ((i & d) == 0) CE(a0 + i, a0 + i + d);
                }
            }
        };
        MERGE(0, 16);
        MERGE(32, 48);
        MERGE(0, 32);
    }
#pragma unroll
    for (int t = 0; t < 16; ++t) f[17 + t] = v[t] * inv_n;

    // ================= MLP via MFMA =================
    const int w = tid >> 6, l = tid & 63;
    _Float16 (*act)[64] = sAct[w];

    // pack features (f16) into act row l, zero-padded to K=64
#pragma unroll
    for (int q = 0; q < 8; ++q) {
        half8 p;
#pragma unroll
        for (int e = 0; e < 8; ++e) {
            const int k = q * 8 + e;
            p[e] = (k < 33) ? (_Float16)f[k] : (_Float16)0.0f;
        }
        *(half8*)&act[l][q * 8] = p;
    }
    asm volatile("s_waitcnt lgkmcnt(0)" ::: "memory");

    const int rowbase = blockIdx.x * TPB + w * 64;
    mfma_layer<false>(act, sWh[0], sWl[0], sP + 256, sP + 0,   sP + 64,
                      nullptr, 0, 0);
    mfma_layer<false>(act, sWh[1], sWl[1], sP + 320, sP + 128, sP + 192,
                      nullptr, 0, 0);
    mfma_layer<true >(act, sWh[2], sWl[2], sP + 384, nullptr,  nullptr,
                      out, rowbase, nrows);
}

extern "C" void kernel_launch(void* const* d_in, const int* in_sizes, int n_in,
                              void* d_out, int out_size, void* d_ws, size_t ws_size,
                              hipStream_t stream) {
    const int*   tt  = (const int*)d_in[0];
    // d_in[1] is the Hadamard matrix H -- unused (in-register FWHT)
    const float* W1  = (const float*)d_in[2];
    const float* b1  = (const float*)d_in[3];
    const float* g1  = (const float*)d_in[4];
    const float* be1 = (const float*)d_in[5];
    const float* W2  = (const float*)d_in[6];
    const float* b2  = (const float*)d_in[7];
    const float* g2  = (const float*)d_in[8];
    const float* be2 = (const float*)d_in[9];
    const float* W3  = (const float*)d_in[10];
    const float* b3  = (const float*)d_in[11];
    float* out = (float*)d_out;

    const int nrows = in_sizes[0] / 64;
    const int grid = (nrows + TPB - 1) / TPB;
    hipLaunchKernelGGL(walsh_mlp_kernel, dim3(grid), dim3(TPB), 0, stream,
                       tt, W1, b1, g1, be1, W2, b2, g2, be2, W3, b3, out, nrows);
}